// Round 3
// baseline (272.823 us; speedup 1.0000x reference)
//
#include <hip/hip_runtime.h>
#include <hip/hip_bf16.h>
#include <cstddef>
#include <cstdint>

// Problem constants: B=4, T=2048, C=1024, NH=16, hs=64, M = B*T = 8192
#define B_DIM 4
#define T_DIM 2048
#define C_DIM 1024
#define NHEAD 16
#define HS    64
#define QKV_LD 3072   // fused QKV row stride (3*C)

// log2(e)/8 : folded into the Wq bf16 cast so QK^T emerges in exp2-domain.
#define QSCALE 0.18033688011112042f

typedef __attribute__((ext_vector_type(8))) short short8;   // 8 bf16 (MFMA A/B frag)
typedef __attribute__((ext_vector_type(4))) float f32x4;    // MFMA C/D frag

__device__ __forceinline__ short f2bf(float x) {
    __hip_bfloat16 b = __float2bfloat16(x);   // RNE
    return *reinterpret_cast<short*>(&b);
}

// async global->LDS, 16B per lane; LDS dest is wave-uniform base + lane*16.
__device__ __forceinline__ void load_lds16(const void* g, void* l) {
    __builtin_amdgcn_global_load_lds(
        (const __attribute__((address_space(1))) void*)(g),
        (__attribute__((address_space(3))) void*)(l),
        16, 0, 0);
}

// ---------------------------------------------------------------------------
// cast fp32 -> bf16 (with optional fp32 pre-scale), 8 elements/thread
// ---------------------------------------------------------------------------
__global__ __launch_bounds__(256) void cast_bf16(
    const float* __restrict__ in, short* __restrict__ out, int n8, float scale)
{
    int i = blockIdx.x * 256 + threadIdx.x;
    if (i >= n8) return;
    const float4* p = (const float4*)in + (size_t)i * 2;
    float4 a = p[0], b = p[1];
    short8 o;
    o[0]=f2bf(a.x*scale); o[1]=f2bf(a.y*scale); o[2]=f2bf(a.z*scale); o[3]=f2bf(a.w*scale);
    o[4]=f2bf(b.x*scale); o[5]=f2bf(b.y*scale); o[6]=f2bf(b.z*scale); o[7]=f2bf(b.w*scale);
    *((short8*)out + i) = o;
}

// ---------------------------------------------------------------------------
// 8-phase 256x256 MFMA GEMM (T2+T3+T4+T5): C[M,N] = A[M,K] @ B[N,K]^T,
// bf16 in/out, fp32 accumulate. BK=64, 8 waves (2M x 4N), 512 threads,
// 128 KiB double-buffered LDS, per-wave acc 128x64 = acc[8][4].
// ---------------------------------------------------------------------------
__global__ __launch_bounds__(512, 2) void gemm_bt_8ph(
    const short* __restrict__ A,    // [M,K] bf16
    const short* __restrict__ Bm,   // [N,K] bf16
    short* __restrict__ Cm,         // [M,N] bf16
    int M, int N, int K)
{
    __shared__ __align__(16) short lds[65536];   // A0|A1|B0|B1, 32KB each

    // bijective XCD swizzle (gridDim.x % 8 == 0), then flat -> (bx,by)
    const int nbx = N >> 8;
    int wg = blockIdx.x;
    const int cpx = gridDim.x >> 3;
    wg = (wg & 7) * cpx + (wg >> 3);
    const int bx = wg % nbx, by = wg / nbx;
    const int m0 = by << 8, n0 = bx << 8;

    const int t = threadIdx.x;
    const int w = t >> 6, lane = t & 63;
    const int l16 = lane & 15, quad = lane >> 4;
    const int wm = w >> 2, wn = w & 3;

    // staging geometry: one call = 64 rows x 128B, thread -> (row, 16B chunk)
    const int rcall  = t >> 3;                  // 0..63
    const int chunk  = t & 7;
    const int schunk = chunk ^ (rcall & 7);     // pre-swizzled source chunk
    const int dstrow = w * 8;                   // per-wave linear LDS row base

    const short* AgT = A  + (size_t)(m0 + rcall) * K + schunk * 8;  // rows 0..127
    const short* AgB = AgT + (size_t)128 * K;                       // rows 128..255
    const short* BgT = Bm + (size_t)(n0 + rcall) * K + schunk * 8;
    const short* BgB = BgT + (size_t)128 * K;

    // frag read offsets (shorts within a 256x64 tile), swizzled
    int aoff[8][2], boff[4][2];
    #pragma unroll
    for (int mf = 0; mf < 8; ++mf) {
        const int ar = wm * 128 + mf * 16 + l16;
        #pragma unroll
        for (int ks = 0; ks < 2; ++ks)
            aoff[mf][ks] = ar * 64 + (((ks * 4 + quad) ^ (ar & 7)) * 8);
    }
    #pragma unroll
    for (int nf = 0; nf < 4; ++nf) {
        const int br = wn * 64 + nf * 16 + l16;
        #pragma unroll
        for (int ks = 0; ks < 2; ++ks)
            boff[nf][ks] = br * 64 + (((ks * 4 + quad) ^ (br & 7)) * 8);
    }

    f32x4 acc[8][4];
    const f32x4 zero4 = {0.f, 0.f, 0.f, 0.f};
    #pragma unroll
    for (int mf = 0; mf < 8; ++mf)
        #pragma unroll
        for (int nf = 0; nf < 4; ++nf) acc[mf][nf] = zero4;

    const int NT = K >> 6;   // 64-wide K-tiles

    #define STAGE_HALF(gbase, kt, lhalf)                                        \
        {                                                                        \
            load_lds16((gbase) + (size_t)(kt) * 64,                              \
                       (lhalf) + dstrow * 64);                                   \
            load_lds16((gbase) + (size_t)64 * K + (size_t)(kt) * 64,             \
                       (lhalf) + (64 + dstrow) * 64);                            \
        }

    // prologue: tile0 fully + tile1.A0
    STAGE_HALF(AgT, 0, lds);                    // t0.A0 -> bufA0
    STAGE_HALF(AgB, 0, lds + 128 * 64);         // t0.A1
    STAGE_HALF(BgT, 0, lds + 32768);            // t0.B0
    STAGE_HALF(BgB, 0, lds + 32768 + 128 * 64); // t0.B1
    STAGE_HALF(AgT, 1, lds + 16384);            // t1.A0 -> bufA1

    for (int kt = 0; kt < NT; ++kt) {
        const int b0 = kt & 1;
        const short* Acur = lds + b0 * 16384;
        const short* Bcur = lds + 32768 + b0 * 16384;
        short* Anx = lds + (b0 ^ 1) * 16384;
        short* Bnx = lds + 32768 + (b0 ^ 1) * 16384;

        if (kt == NT - 1) asm volatile("s_waitcnt vmcnt(0)" ::: "memory");
        else              asm volatile("s_waitcnt vmcnt(2)" ::: "memory");
        __builtin_amdgcn_s_barrier();

        // B-frags for the whole tile (persist across phases)
        short8 bfr[4][2];
        #pragma unroll
        for (int nf = 0; nf < 4; ++nf)
            #pragma unroll
            for (int ks = 0; ks < 2; ++ks)
                bfr[nf][ks] = *(const short8*)(Bcur + boff[nf][ks]);

        #pragma unroll
        for (int ph = 0; ph < 4; ++ph) {
            short8 af[2][2];
            #pragma unroll
            for (int r = 0; r < 2; ++r)
                #pragma unroll
                for (int ks = 0; ks < 2; ++ks)
                    af[r][ks] = *(const short8*)(Acur + aoff[ph * 2 + r][ks]);

            if (ph == 0)      { if (kt + 1 < NT) STAGE_HALF(AgB, kt + 1, Anx + 128 * 64); }
            else if (ph == 1) { if (kt + 1 < NT) STAGE_HALF(BgT, kt + 1, Bnx); }
            else if (ph == 2) { if (kt + 1 < NT) STAGE_HALF(BgB, kt + 1, Bnx + 128 * 64); }

            __builtin_amdgcn_s_barrier();
            __builtin_amdgcn_s_setprio(1);
            #pragma unroll
            for (int r = 0; r < 2; ++r)
                #pragma unroll
                for (int nf = 0; nf < 4; ++nf)
                    #pragma unroll
                    for (int ks = 0; ks < 2; ++ks)
                        acc[ph * 2 + r][nf] = __builtin_amdgcn_mfma_f32_16x16x32_bf16(
                            af[r][ks], bfr[nf][ks], acc[ph * 2 + r][nf], 0, 0, 0);
            __builtin_amdgcn_s_setprio(0);
            __builtin_amdgcn_s_barrier();
        }

        // buf[kt&1] fully consumed (barrier above) -> prefetch (t+2).A0 into it
        if (kt + 2 < NT) { short* Aw = lds + b0 * 16384; STAGE_HALF(AgT, kt + 2, Aw); }
    }
    #undef STAGE_HALF

    #pragma unroll
    for (int mf = 0; mf < 8; ++mf) {
        const int row_base = m0 + wm * 128 + mf * 16 + quad * 4;
        #pragma unroll
        for (int nf = 0; nf < 4; ++nf) {
            const int col = n0 + wn * 64 + nf * 16 + l16;
            #pragma unroll
            for (int r = 0; r < 4; ++r)
                Cm[(size_t)(row_base + r) * N + col] = f2bf(acc[mf][nf][r]);
        }
    }
}

// ---------------------------------------------------------------------------
// MFMA GEMM: C[M,N] = A[M,K] @ B[N,K]^T, bf16 in, fp32 accumulate.
// 128x128 tile, BK=32, 4 waves (2x2), 16x16x32 MFMA, global_load_lds w=16,
// XOR-swizzled LDS. (Retained for the output projection, fp32 out.)
// ---------------------------------------------------------------------------
#define BM 128
#define BN 128
#define BK 32

template<bool OUT_BF16>
__global__ __launch_bounds__(256) void gemm_bt_mfma(
    const short* __restrict__ A,
    const short* __restrict__ Bm,
    void* __restrict__ Cm,
    int M, int N, int K, float scale)
{
    __shared__ __align__(16) short smem[8192];   // As 8KB | Bs 8KB
    short* As = smem;
    short* Bs = smem + 4096;

    const int m0 = blockIdx.y * BM;
    const int n0 = blockIdx.x * BN;
    const int t    = threadIdx.x;
    const int w    = t >> 6;
    const int lane = t & 63;
    const int l16  = lane & 15;
    const int quad = lane >> 4;
    const int wm   = w >> 1;
    const int wn   = w & 1;

    const int mS0 = t >> 2;
    const int qS  = (t & 3) ^ ((t >> 3) & 3);
    const short* aG0 = A  + (size_t)(m0 + mS0)      * K + qS * 8;
    const short* aG1 = A  + (size_t)(m0 + mS0 + 64) * K + qS * 8;
    const short* bG0 = Bm + (size_t)(n0 + mS0)      * K + qS * 8;
    const short* bG1 = Bm + (size_t)(n0 + mS0 + 64) * K + qS * 8;
    short* aL0 = As + (size_t)(w * 64) * 8;
    short* aL1 = As + (size_t)(256 + w * 64) * 8;
    short* bL0 = Bs + (size_t)(w * 64) * 8;
    short* bL1 = Bs + (size_t)(256 + w * 64) * 8;

    int a_off[4], b_off[4];
    #pragma unroll
    for (int i = 0; i < 4; ++i) {
        int am = wm * 64 + i * 16 + l16;
        a_off[i] = (am * 4 + (quad ^ ((am >> 1) & 3))) * 8;
        int bn = wn * 64 + i * 16 + l16;
        b_off[i] = (bn * 4 + (quad ^ ((bn >> 1) & 3))) * 8;
    }

    f32x4 acc[4][4];
    const f32x4 zero4 = {0.f, 0.f, 0.f, 0.f};
    #pragma unroll
    for (int i = 0; i < 4; ++i)
        #pragma unroll
        for (int j = 0; j < 4; ++j) acc[i][j] = zero4;

    for (int k0 = 0; k0 < K; k0 += BK) {
        __syncthreads();
        load_lds16(aG0 + k0, aL0);
        load_lds16(aG1 + k0, aL1);
        load_lds16(bG0 + k0, bL0);
        load_lds16(bG1 + k0, bL1);
        __syncthreads();

        short8 af[4], bf[4];
        #pragma unroll
        for (int i = 0; i < 4; ++i) {
            af[i] = *(const short8*)(As + a_off[i]);
            bf[i] = *(const short8*)(Bs + b_off[i]);
        }
        #pragma unroll
        for (int i = 0; i < 4; ++i)
            #pragma unroll
            for (int j = 0; j < 4; ++j)
                acc[i][j] = __builtin_amdgcn_mfma_f32_16x16x32_bf16(
                    af[i], bf[j], acc[i][j], 0, 0, 0);
    }

    #pragma unroll
    for (int i = 0; i < 4; ++i) {
        const int row_base = m0 + wm * 64 + i * 16 + quad * 4;
        #pragma unroll
        for (int j = 0; j < 4; ++j) {
            const int col = n0 + wn * 64 + j * 16 + l16;
            #pragma unroll
            for (int r = 0; r < 4; ++r) {
                const size_t idx = (size_t)(row_base + r) * N + col;
                if (OUT_BF16) ((short*)Cm)[idx] = f2bf(acc[i][j][r] * scale);
                else          ((float*)Cm)[idx] = acc[i][j][r] * scale;
            }
        }
    }
}

// ---------------------------------------------------------------------------
// Transpose V: bf16 [B,T,srcLD] (head-interleaved cols) -> bf16 [B,NH,HS,T]
// ---------------------------------------------------------------------------
__global__ __launch_bounds__(256) void transpose_v(
    const short* __restrict__ Vb,
    short* __restrict__ Vt, int srcLD)
{
    const int t0 = blockIdx.x * 64;
    const int head = blockIdx.y;              // b*NHEAD + h
    const int b = head >> 4, h = head & 15;

    __shared__ short Ls[64][72];

    const int t = threadIdx.x;
    const int r = t >> 2;
    const int c = (t & 3) * 16;

    const short* src = Vb + ((size_t)(b * T_DIM) + t0 + r) * srcLD + h * HS + c;
    *(short8*)&Ls[r][c]     = *(const short8*)src;
    *(short8*)&Ls[r][c + 8] = *(const short8*)(src + 8);
    __syncthreads();

    short tmp[16];
    #pragma unroll
    for (int i = 0; i < 16; ++i) tmp[i] = Ls[c + i][r];
    short* dst = Vt + ((size_t)head * HS + r) * T_DIM + t0 + c;
    *(short8*)dst       = *(short8*)&tmp[0];
    *(short8*)(dst + 8) = *(short8*)&tmp[8];
}

// ---------------------------------------------------------------------------
// Flash attention v5: v4 + T14 async-STAGE split + T5 setprio.
//  - T14: next tile's K/V global loads are ISSUED right after the staging
//    barrier, so ~500cy HBM/L2 latency hides under the current tile's
//    MFMA/exp compute (~1750cy). The loop-top __syncthreads() (which drains
//    vmcnt) retires them before the ds_write — no explicit waitcnt needed.
//  - T5: setprio(1) around the per-sub l+PV MFMA cluster.
//  - Q pre-scaled by log2(e)/8 at the Wq cast -> exp is a bare v_exp_f32.
//  - Row-sum l computed by MFMA against a ones B-fragment.
// One block = one (b,h) head x 256 q-rows (4 subtiles of 64); 4 waves.
// S^T trick: A=K-frag, B=Q-frag -> D[key][q]; K rows permuted kappa^-1 so
// exp'd S^T regs concatenate directly into the PV A-fragment. No-max softmax.
// ---------------------------------------------------------------------------
#define QSUB 4

__global__ __launch_bounds__(256, 2) void attn_mfma3(
    const short* __restrict__ Qb,    // [B,T,QKV_LD], Q cols (pre-scaled)
    const short* __restrict__ Kb,    // [B,T,QKV_LD], K cols
    const short* __restrict__ Vt,    // [B*NH, HS, T]
    short* __restrict__ O)           // [B,T,C] bf16
{
    const int i0   = blockIdx.x * (64 * QSUB);
    const int head = blockIdx.y;
    const int b = head >> 4, h = head & 15;

    const int t    = threadIdx.x;
    const int w    = t >> 6;
    const int lane = t & 63;
    const int l16  = lane & 15;
    const int quad = lane >> 4;

    __shared__ short Ks[64][72];     // [perm key][dim]
    __shared__ short Vts[64][72];    // [dim][key]

    short8 qf[QSUB][2];
    #pragma unroll
    for (int sub = 0; sub < QSUB; ++sub) {
        const short* qrow = Qb
            + ((size_t)(b * T_DIM) + i0 + sub * 64 + w * 16 + l16) * QKV_LD + h * HS;
        qf[sub][0] = *(const short8*)(qrow + quad * 8);
        qf[sub][1] = *(const short8*)(qrow + 32 + quad * 8);
    }

    short8 onesv;
    #pragma unroll
    for (int j = 0; j < 8; ++j) onesv[j] = (short)0x3F80;

    const f32x4 zero4 = {0.f, 0.f, 0.f, 0.f};
    f32x4 oacc[QSUB][4];
    f32x4 lacc[QSUB];
    #pragma unroll
    for (int sub = 0; sub < QSUB; ++sub) {
        #pragma unroll
        for (int dg = 0; dg < 4; ++dg) oacc[sub][dg] = zero4;
        lacc[sub] = zero4;
    }

    const int sr = t >> 2;
    const int sc = (t & 3) * 16;
    const int krow = (sr & 32) | ((sr & 4) << 2) | ((sr & 24) >> 1) | (sr & 3);
    const short* kgbase = Kb + (size_t)(b * T_DIM) * QKV_LD + h * HS;
    const short* vgbase = Vt + ((size_t)head * HS + sr) * T_DIM;

    // T14 prologue: tile 0 K/V -> regs
    short8 kr0, kr1, vr0, vr1;
    {
        const short* kp = kgbase + (size_t)sr * QKV_LD + sc;
        kr0 = *(const short8*)kp;
        kr1 = *(const short8*)(kp + 8);
        vr0 = *(const short8*)(vgbase + sc);
        vr1 = *(const short8*)(vgbase + sc + 8);
    }

    for (int j0 = 0; j0 < T_DIM; j0 += 64) {
        __syncthreads();                     // prev tile reads done + vmcnt drain
        *(short8*)&Ks[krow][sc]     = kr0;
        *(short8*)&Ks[krow][sc + 8] = kr1;
        *(short8*)&Vts[sr][sc]      = vr0;
        *(short8*)&Vts[sr][sc + 8]  = vr1;
        __syncthreads();

        // T14: issue next tile's global loads now; they complete under compute
        if (j0 + 64 < T_DIM) {
            const short* kp = kgbase + (size_t)(j0 + 64 + sr) * QKV_LD + sc;
            kr0 = *(const short8*)kp;
            kr1 = *(const short8*)(kp + 8);
            const short* vp = vgbase + j0 + 64;
            vr0 = *(const short8*)(vp + sc);
            vr1 = *(const short8*)(vp + sc + 8);
        }

        short8 ka[4][2], va[4][2];
        #pragma unroll
        for (int kt = 0; kt < 4; ++kt) {
            ka[kt][0] = *(const short8*)&Ks[kt * 16 + l16][quad * 8];
            ka[kt][1] = *(const short8*)&Ks[kt * 16 + l16][32 + quad * 8];
            va[kt][0] = *(const short8*)&Vts[kt * 16 + l16][quad * 8];
            va[kt][1] = *(const short8*)&Vts[kt * 16 + l16][32 + quad * 8];
        }

        #pragma unroll
        for (int sub = 0; sub < QSUB; ++sub) {
            f32x4 s[4];
            #pragma unroll
            for (int kt = 0; kt < 4; ++kt) {
                f32x4 acc = zero4;
                acc = __builtin_amdgcn_mfma_f32_16x16x32_bf16(ka[kt][0], qf[sub][0], acc, 0, 0, 0);
                acc = __builtin_amdgcn_mfma_f32_16x16x32_bf16(ka[kt][1], qf[sub][1], acc, 0, 0, 0);
                s[kt] = acc;
            }

            short8 pa[2];
            #pragma unroll
            for (int hh = 0; hh < 2; ++hh) {
                #pragma unroll
                for (int c = 0; c < 2; ++c) {
                    f32x4 sv = s[2 * hh + c];
                    #pragma unroll
                    for (int r = 0; r < 4; ++r) {
                        float p = __builtin_amdgcn_exp2f(sv[r]);
                        pa[hh][c * 4 + r] = f2bf(p);
                    }
                }
            }

            __builtin_amdgcn_s_setprio(1);
            lacc[sub] = __builtin_amdgcn_mfma_f32_16x16x32_bf16(pa[0], onesv, lacc[sub], 0, 0, 0);
            lacc[sub] = __builtin_amdgcn_mfma_f32_16x16x32_bf16(pa[1], onesv, lacc[sub], 0, 0, 0);

            #pragma unroll
            for (int dg = 0; dg < 4; ++dg) {
                oacc[sub][dg] = __builtin_amdgcn_mfma_f32_16x16x32_bf16(pa[0], va[dg][0], oacc[sub][dg], 0, 0, 0);
                oacc[sub][dg] = __builtin_amdgcn_mfma_f32_16x16x32_bf16(pa[1], va[dg][1], oacc[sub][dg], 0, 0, 0);
            }
            __builtin_amdgcn_s_setprio(0);
        }
    }

    #pragma unroll
    for (int sub = 0; sub < QSUB; ++sub) {
        float linv[4];
        #pragma unroll
        for (int r = 0; r < 4; ++r) linv[r] = 1.0f / lacc[sub][r];

        #pragma unroll
        for (int r = 0; r < 4; ++r) {
            short* orow = O + ((size_t)(b * T_DIM) + i0 + sub * 64 + w * 16 + quad * 4 + r) * C_DIM + h * HS;
            #pragma unroll
            for (int dg = 0; dg < 4; ++dg)
                orow[dg * 16 + l16] = f2bf(oacc[sub][dg][r] * linv[r]);
        }
    }
}

// ---------------------------------------------------------------------------
// ws layout (bytes), NB = 2*M*C = 16.8MB, WB = 2*C*C = 2.1MB:
//   [0]      xb bf16 (reused as Ob after QKV gemm)
//   [NB]     QKVb bf16 [M,3C]  (3*NB)
//   [4NB]    Vt bf16 [B*NH,HS,T]
//   [5NB]    W3b (Wq|Wk|Wv rows, 3*WB) | Wob (WB)      total 92.4MB
// ---------------------------------------------------------------------------
extern "C" void kernel_launch(void* const* d_in, const int* in_sizes, int n_in,
                              void* d_out, int out_size, void* d_ws, size_t ws_size,
                              hipStream_t stream) {
    const float* x  = (const float*)d_in[0];
    const float* Wk = (const float*)d_in[1];
    const float* Wq = (const float*)d_in[2];
    const float* Wv = (const float*)d_in[3];
    const float* Wo = (const float*)d_in[4];
    float* out = (float*)d_out;

    const int M = B_DIM * T_DIM;                       // 8192
    const size_t NE = (size_t)M * C_DIM;               // 8.4M
    const size_t NB = 2 * NE;                          // bytes
    const size_t WB = (size_t)2 * C_DIM * C_DIM;
    const size_t WE = (size_t)C_DIM * C_DIM;           // elements

    char* ws = (char*)d_ws;
    short* xb   = (short*)(ws);
    short* Ob   = xb;                                  // reuse after QKV gemm
    short* QKVb = (short*)(ws + NB);
    short* Vtb  = (short*)(ws + 4 * NB);
    short* W3b  = (short*)(ws + 5 * NB);               // [3C, C] rows: Wq|Wk|Wv
    short* Wob  = (short*)(ws + 5 * NB + 3 * WB);

    // casts (Wq pre-scaled by log2(e)/8: QK^T lands in exp2-domain)
    cast_bf16<<<(int)(NE / 8 / 256), 256, 0, stream>>>(x, xb, (int)(NE / 8), 1.0f);
    const int wn8 = (int)(WE / 8);                     // 131072
    cast_bf16<<<wn8 / 256, 256, 0, stream>>>(Wq, W3b,          wn8, QSCALE);
    cast_bf16<<<wn8 / 256, 256, 0, stream>>>(Wk, W3b + WE,     wn8, 1.0f);
    cast_bf16<<<wn8 / 256, 256, 0, stream>>>(Wv, W3b + 2 * WE, wn8, 1.0f);
    cast_bf16<<<wn8 / 256, 256, 0, stream>>>(Wo, Wob,          wn8, 1.0f);

    // fused QKV projection: [M,3C] = xb @ W3^T  (8-phase 256^2, grid 384)
    gemm_bt_8ph<<<dim3((QKV_LD / 256) * (M / 256)), 512, 0, stream>>>(
        xb, W3b, QKVb, M, QKV_LD, C_DIM);

    // V transpose to [B*NH, HS, T]
    transpose_v<<<dim3(T_DIM / 64, B_DIM * NHEAD), 256, 0, stream>>>(
        QKVb + 2 * C_DIM, Vtb, QKV_LD);

    // attention (4x q-merge)
    attn_mfma3<<<dim3(T_DIM / (64 * QSUB), B_DIM * NHEAD), 256, 0, stream>>>(
        QKVb, QKVb + C_DIM, Vtb, Ob);

    // output projection (fp32 out)
    gemm_bt_mfma<false><<<dim3(C_DIM / BN, M / BM), 256, 0, stream>>>(
        Ob, Wob, out, M, C_DIM, C_DIM, 1.0f);
}

// Round 5
// 262.624 us; speedup vs baseline: 1.0388x; 1.0388x over previous
//
#include <hip/hip_runtime.h>
#include <hip/hip_bf16.h>
#include <cstddef>
#include <cstdint>

// Problem constants: B=4, T=2048, C=1024, NH=16, hs=64, M = B*T = 8192
#define B_DIM 4
#define T_DIM 2048
#define C_DIM 1024
#define NHEAD 16
#define HS    64
#define QKV_LD 3072   // fused QKV row stride (3*C)

// log2(e)/8 : folded into the Wq bf16 cast so QK^T emerges in exp2-domain.
#define QSCALE 0.18033688011112042f

typedef __attribute__((ext_vector_type(8))) short short8;   // 8 bf16 (MFMA A/B frag)
typedef __attribute__((ext_vector_type(4))) float f32x4;    // MFMA C/D frag

__device__ __forceinline__ short f2bf(float x) {
    __hip_bfloat16 b = __float2bfloat16(x);   // RNE
    return *reinterpret_cast<short*>(&b);
}

// async global->LDS, 16B per lane; LDS dest is wave-uniform base + lane*16.
__device__ __forceinline__ void load_lds16(const void* g, void* l) {
    __builtin_amdgcn_global_load_lds(
        (const __attribute__((address_space(1))) void*)(g),
        (__attribute__((address_space(3))) void*)(l),
        16, 0, 0);
}

// ---------------------------------------------------------------------------
// cast fp32 -> bf16 (with optional fp32 pre-scale), 8 elements/thread
// ---------------------------------------------------------------------------
__global__ __launch_bounds__(256) void cast_bf16(
    const float* __restrict__ in, short* __restrict__ out, int n8, float scale)
{
    int i = blockIdx.x * 256 + threadIdx.x;
    if (i >= n8) return;
    const float4* p = (const float4*)in + (size_t)i * 2;
    float4 a = p[0], b = p[1];
    short8 o;
    o[0]=f2bf(a.x*scale); o[1]=f2bf(a.y*scale); o[2]=f2bf(a.z*scale); o[3]=f2bf(a.w*scale);
    o[4]=f2bf(b.x*scale); o[5]=f2bf(b.y*scale); o[6]=f2bf(b.z*scale); o[7]=f2bf(b.w*scale);
    *((short8*)out + i) = o;
}

// 4 weight matrices (Wq|Wk|Wv|Wo) -> one contiguous bf16 region (W3b|Wob).
// blockIdx.y selects source; Wq gets QSCALE folded in.
__global__ __launch_bounds__(256) void cast4_bf16(
    const float* __restrict__ w0, const float* __restrict__ w1,
    const float* __restrict__ w2, const float* __restrict__ w3,
    short* __restrict__ out, int n8)
{
    int i = blockIdx.x * 256 + threadIdx.x;
    if (i >= n8) return;
    const int sel = blockIdx.y;
    const float* in = (sel == 0) ? w0 : (sel == 1) ? w1 : (sel == 2) ? w2 : w3;
    const float scale = (sel == 0) ? QSCALE : 1.0f;
    const float4* p = (const float4*)in + (size_t)i * 2;
    float4 a = p[0], b = p[1];
    short8 o;
    o[0]=f2bf(a.x*scale); o[1]=f2bf(a.y*scale); o[2]=f2bf(a.z*scale); o[3]=f2bf(a.w*scale);
    o[4]=f2bf(b.x*scale); o[5]=f2bf(b.y*scale); o[6]=f2bf(b.z*scale); o[7]=f2bf(b.w*scale);
    *((short8*)out + (size_t)sel * n8 + i) = o;
}

// ---------------------------------------------------------------------------
// 8-phase 256x256 MFMA GEMM (T2+T3+T4+T5): C[M,N] = A[M,K] @ B[N,K]^T,
// bf16 in/out, fp32 accumulate. BK=64, 8 waves (2M x 4N), 512 threads,
// 128 KiB double-buffered LDS, per-wave acc 128x64 = acc[8][4].
// ---------------------------------------------------------------------------
__global__ __launch_bounds__(512, 2) void gemm_bt_8ph(
    const short* __restrict__ A,    // [M,K] bf16
    const short* __restrict__ Bm,   // [N,K] bf16
    short* __restrict__ Cm,         // [M,N] bf16
    int M, int N, int K)
{
    __shared__ __align__(16) short lds[65536];   // A0|A1|B0|B1, 32KB each

    // bijective XCD swizzle (gridDim.x % 8 == 0), then flat -> (bx,by)
    const int nbx = N >> 8;
    int wg = blockIdx.x;
    const int cpx = gridDim.x >> 3;
    wg = (wg & 7) * cpx + (wg >> 3);
    const int bx = wg % nbx, by = wg / nbx;
    const int m0 = by << 8, n0 = bx << 8;

    const int t = threadIdx.x;
    const int w = t >> 6, lane = t & 63;
    const int l16 = lane & 15, quad = lane >> 4;
    const int wm = w >> 2, wn = w & 3;

    // staging geometry: one call = 64 rows x 128B, thread -> (row, 16B chunk)
    const int rcall  = t >> 3;                  // 0..63
    const int chunk  = t & 7;
    const int schunk = chunk ^ (rcall & 7);     // pre-swizzled source chunk
    const int dstrow = w * 8;                   // per-wave linear LDS row base

    const short* AgT = A  + (size_t)(m0 + rcall) * K + schunk * 8;  // rows 0..127
    const short* AgB = AgT + (size_t)128 * K;                       // rows 128..255
    const short* BgT = Bm + (size_t)(n0 + rcall) * K + schunk * 8;
    const short* BgB = BgT + (size_t)128 * K;

    // frag read offsets (shorts within a 256x64 tile), swizzled
    int aoff[8][2], boff[4][2];
    #pragma unroll
    for (int mf = 0; mf < 8; ++mf) {
        const int ar = wm * 128 + mf * 16 + l16;
        #pragma unroll
        for (int ks = 0; ks < 2; ++ks)
            aoff[mf][ks] = ar * 64 + (((ks * 4 + quad) ^ (ar & 7)) * 8);
    }
    #pragma unroll
    for (int nf = 0; nf < 4; ++nf) {
        const int br = wn * 64 + nf * 16 + l16;
        #pragma unroll
        for (int ks = 0; ks < 2; ++ks)
            boff[nf][ks] = br * 64 + (((ks * 4 + quad) ^ (br & 7)) * 8);
    }

    f32x4 acc[8][4];
    const f32x4 zero4 = {0.f, 0.f, 0.f, 0.f};
    #pragma unroll
    for (int mf = 0; mf < 8; ++mf)
        #pragma unroll
        for (int nf = 0; nf < 4; ++nf) acc[mf][nf] = zero4;

    const int NT = K >> 6;   // 64-wide K-tiles

    #define STAGE_HALF(gbase, kt, lhalf)                                        \
        {                                                                        \
            load_lds16((gbase) + (size_t)(kt) * 64,                              \
                       (lhalf) + dstrow * 64);                                   \
            load_lds16((gbase) + (size_t)64 * K + (size_t)(kt) * 64,             \
                       (lhalf) + (64 + dstrow) * 64);                            \
        }

    // prologue: tile0 fully + tile1.A0
    STAGE_HALF(AgT, 0, lds);                    // t0.A0 -> bufA0
    STAGE_HALF(AgB, 0, lds + 128 * 64);         // t0.A1
    STAGE_HALF(BgT, 0, lds + 32768);            // t0.B0
    STAGE_HALF(BgB, 0, lds + 32768 + 128 * 64); // t0.B1
    STAGE_HALF(AgT, 1, lds + 16384);            // t1.A0 -> bufA1

    for (int kt = 0; kt < NT; ++kt) {
        const int b0 = kt & 1;
        const short* Acur = lds + b0 * 16384;
        const short* Bcur = lds + 32768 + b0 * 16384;
        short* Anx = lds + (b0 ^ 1) * 16384;
        short* Bnx = lds + 32768 + (b0 ^ 1) * 16384;

        if (kt == NT - 1) asm volatile("s_waitcnt vmcnt(0)" ::: "memory");
        else              asm volatile("s_waitcnt vmcnt(2)" ::: "memory");
        __builtin_amdgcn_s_barrier();

        // B-frags for the whole tile (persist across phases)
        short8 bfr[4][2];
        #pragma unroll
        for (int nf = 0; nf < 4; ++nf)
            #pragma unroll
            for (int ks = 0; ks < 2; ++ks)
                bfr[nf][ks] = *(const short8*)(Bcur + boff[nf][ks]);

        #pragma unroll
        for (int ph = 0; ph < 4; ++ph) {
            short8 af[2][2];
            #pragma unroll
            for (int r = 0; r < 2; ++r)
                #pragma unroll
                for (int ks = 0; ks < 2; ++ks)
                    af[r][ks] = *(const short8*)(Acur + aoff[ph * 2 + r][ks]);

            if (ph == 0)      { if (kt + 1 < NT) STAGE_HALF(AgB, kt + 1, Anx + 128 * 64); }
            else if (ph == 1) { if (kt + 1 < NT) STAGE_HALF(BgT, kt + 1, Bnx); }
            else if (ph == 2) { if (kt + 1 < NT) STAGE_HALF(BgB, kt + 1, Bnx + 128 * 64); }

            __builtin_amdgcn_s_barrier();
            __builtin_amdgcn_s_setprio(1);
            #pragma unroll
            for (int r = 0; r < 2; ++r)
                #pragma unroll
                for (int nf = 0; nf < 4; ++nf)
                    #pragma unroll
                    for (int ks = 0; ks < 2; ++ks)
                        acc[ph * 2 + r][nf] = __builtin_amdgcn_mfma_f32_16x16x32_bf16(
                            af[r][ks], bfr[nf][ks], acc[ph * 2 + r][nf], 0, 0, 0);
            __builtin_amdgcn_s_setprio(0);
            __builtin_amdgcn_s_barrier();
        }

        // buf[kt&1] fully consumed (barrier above) -> prefetch (t+2).A0 into it
        if (kt + 2 < NT) { short* Aw = lds + b0 * 16384; STAGE_HALF(AgT, kt + 2, Aw); }
    }
    #undef STAGE_HALF

    #pragma unroll
    for (int mf = 0; mf < 8; ++mf) {
        const int row_base = m0 + wm * 128 + mf * 16 + quad * 4;
        #pragma unroll
        for (int nf = 0; nf < 4; ++nf) {
            const int col = n0 + wn * 64 + nf * 16 + l16;
            #pragma unroll
            for (int r = 0; r < 4; ++r)
                Cm[(size_t)(row_base + r) * N + col] = f2bf(acc[mf][nf][r]);
        }
    }
}

// ---------------------------------------------------------------------------
// MFMA GEMM: C[M,N] = A[M,K] @ B[N,K]^T, bf16 in, fp32 accumulate.
// 128x128 tile, BK=32, 4 waves (2x2), 16x16x32 MFMA, global_load_lds w=16,
// XOR-swizzled LDS. (Retained for the output projection, fp32 out.)
// ---------------------------------------------------------------------------
#define BM 128
#define BN 128
#define BK 32

template<bool OUT_BF16>
__global__ __launch_bounds__(256) void gemm_bt_mfma(
    const short* __restrict__ A,
    const short* __restrict__ Bm,
    void* __restrict__ Cm,
    int M, int N, int K, float scale)
{
    __shared__ __align__(16) short smem[8192];   // As 8KB | Bs 8KB
    short* As = smem;
    short* Bs = smem + 4096;

    const int m0 = blockIdx.y * BM;
    const int n0 = blockIdx.x * BN;
    const int t    = threadIdx.x;
    const int w    = t >> 6;
    const int lane = t & 63;
    const int l16  = lane & 15;
    const int quad = lane >> 4;
    const int wm   = w >> 1;
    const int wn   = w & 1;

    const int mS0 = t >> 2;
    const int qS  = (t & 3) ^ ((t >> 3) & 3);
    const short* aG0 = A  + (size_t)(m0 + mS0)      * K + qS * 8;
    const short* aG1 = A  + (size_t)(m0 + mS0 + 64) * K + qS * 8;
    const short* bG0 = Bm + (size_t)(n0 + mS0)      * K + qS * 8;
    const short* bG1 = Bm + (size_t)(n0 + mS0 + 64) * K + qS * 8;
    short* aL0 = As + (size_t)(w * 64) * 8;
    short* aL1 = As + (size_t)(256 + w * 64) * 8;
    short* bL0 = Bs + (size_t)(w * 64) * 8;
    short* bL1 = Bs + (size_t)(256 + w * 64) * 8;

    int a_off[4], b_off[4];
    #pragma unroll
    for (int i = 0; i < 4; ++i) {
        int am = wm * 64 + i * 16 + l16;
        a_off[i] = (am * 4 + (quad ^ ((am >> 1) & 3))) * 8;
        int bn = wn * 64 + i * 16 + l16;
        b_off[i] = (bn * 4 + (quad ^ ((bn >> 1) & 3))) * 8;
    }

    f32x4 acc[4][4];
    const f32x4 zero4 = {0.f, 0.f, 0.f, 0.f};
    #pragma unroll
    for (int i = 0; i < 4; ++i)
        #pragma unroll
        for (int j = 0; j < 4; ++j) acc[i][j] = zero4;

    for (int k0 = 0; k0 < K; k0 += BK) {
        __syncthreads();
        load_lds16(aG0 + k0, aL0);
        load_lds16(aG1 + k0, aL1);
        load_lds16(bG0 + k0, bL0);
        load_lds16(bG1 + k0, bL1);
        __syncthreads();

        short8 af[4], bf[4];
        #pragma unroll
        for (int i = 0; i < 4; ++i) {
            af[i] = *(const short8*)(As + a_off[i]);
            bf[i] = *(const short8*)(Bs + b_off[i]);
        }
        #pragma unroll
        for (int i = 0; i < 4; ++i)
            #pragma unroll
            for (int j = 0; j < 4; ++j)
                acc[i][j] = __builtin_amdgcn_mfma_f32_16x16x32_bf16(
                    af[i], bf[j], acc[i][j], 0, 0, 0);
    }

    #pragma unroll
    for (int i = 0; i < 4; ++i) {
        const int row_base = m0 + wm * 64 + i * 16 + quad * 4;
        #pragma unroll
        for (int j = 0; j < 4; ++j) {
            const int col = n0 + wn * 64 + j * 16 + l16;
            #pragma unroll
            for (int r = 0; r < 4; ++r) {
                const size_t idx = (size_t)(row_base + r) * N + col;
                if (OUT_BF16) ((short*)Cm)[idx] = f2bf(acc[i][j][r] * scale);
                else          ((float*)Cm)[idx] = acc[i][j][r] * scale;
            }
        }
    }
}

// ---------------------------------------------------------------------------
// Transpose V: bf16 [B,T,srcLD] (head-interleaved cols) -> bf16 [B,NH,HS,T]
// ---------------------------------------------------------------------------
__global__ __launch_bounds__(256) void transpose_v(
    const short* __restrict__ Vb,
    short* __restrict__ Vt, int srcLD)
{
    const int t0 = blockIdx.x * 64;
    const int head = blockIdx.y;              // b*NHEAD + h
    const int b = head >> 4, h = head & 15;

    __shared__ short Ls[64][72];

    const int t = threadIdx.x;
    const int r = t >> 2;
    const int c = (t & 3) * 16;

    const short* src = Vb + ((size_t)(b * T_DIM) + t0 + r) * srcLD + h * HS + c;
    *(short8*)&Ls[r][c]     = *(const short8*)src;
    *(short8*)&Ls[r][c + 8] = *(const short8*)(src + 8);
    __syncthreads();

    short tmp[16];
    #pragma unroll
    for (int i = 0; i < 16; ++i) tmp[i] = Ls[c + i][r];
    short* dst = Vt + ((size_t)head * HS + r) * T_DIM + t0 + c;
    *(short8*)dst       = *(short8*)&tmp[0];
    *(short8*)(dst + 8) = *(short8*)&tmp[8];
}

// ---------------------------------------------------------------------------
// Flash attention v6: R2 structure + T2 chunk-XOR LDS swizzle.
//  - Ks/Vts are [64][64] (128B rows); 16B chunk c of physical row r is
//    stored at chunk (c ^ (r&7)). Same XOR applied on the reg-staged write
//    and the fragment ds_read_b128 -> bank-conflict-free (T2, m214 v20).
//  - Q pre-scaled by log2(e)/8 at the Wq cast -> exp is a bare v_exp_f32.
//  - Row-sum l computed by MFMA against a ones B-fragment.
// One block = one (b,h) head x 256 q-rows (4 subtiles of 64); 4 waves.
// S^T trick: A=K-frag, B=Q-frag -> D[key][q]; K rows permuted kappa^-1 so
// exp'd S^T regs concatenate directly into the PV A-fragment. No-max softmax.
// ---------------------------------------------------------------------------
#define QSUB 4

__global__ __launch_bounds__(256, 2) void attn_mfma3(
    const short* __restrict__ Qb,    // [B,T,QKV_LD], Q cols (pre-scaled)
    const short* __restrict__ Kb,    // [B,T,QKV_LD], K cols
    const short* __restrict__ Vt,    // [B*NH, HS, T]
    short* __restrict__ O)           // [B,T,C] bf16
{
    const int i0   = blockIdx.x * (64 * QSUB);
    const int head = blockIdx.y;
    const int b = head >> 4, h = head & 15;

    const int t    = threadIdx.x;
    const int w    = t >> 6;
    const int lane = t & 63;
    const int l16  = lane & 15;
    const int quad = lane >> 4;

    __shared__ __align__(16) short Ks[64][64];    // [perm key][dim], chunk-swizzled
    __shared__ __align__(16) short Vts[64][64];   // [dim][key],     chunk-swizzled

    short8 qf[QSUB][2];
    #pragma unroll
    for (int sub = 0; sub < QSUB; ++sub) {
        const short* qrow = Qb
            + ((size_t)(b * T_DIM) + i0 + sub * 64 + w * 16 + l16) * QKV_LD + h * HS;
        qf[sub][0] = *(const short8*)(qrow + quad * 8);
        qf[sub][1] = *(const short8*)(qrow + 32 + quad * 8);
    }

    short8 onesv;
    #pragma unroll
    for (int j = 0; j < 8; ++j) onesv[j] = (short)0x3F80;

    const f32x4 zero4 = {0.f, 0.f, 0.f, 0.f};
    f32x4 oacc[QSUB][4];
    f32x4 lacc[QSUB];
    #pragma unroll
    for (int sub = 0; sub < QSUB; ++sub) {
        #pragma unroll
        for (int dg = 0; dg < 4; ++dg) oacc[sub][dg] = zero4;
        lacc[sub] = zero4;
    }

    const int sr  = t >> 2;                  // staging row 0..63
    const int sc2 = (t & 3) * 2;             // first of two 16B chunks
    const int krow = (sr & 32) | ((sr & 4) << 2) | ((sr & 24) >> 1) | (sr & 3);
    const short* kgbase = Kb + (size_t)(b * T_DIM) * QKV_LD + h * HS;
    const short* vgbase = Vt + ((size_t)head * HS + sr) * T_DIM;

    // swizzled staging destinations (fixed per thread)
    short* kd0 = &Ks[krow][((sc2    ) ^ (krow & 7)) * 8];
    short* kd1 = &Ks[krow][((sc2 + 1) ^ (krow & 7)) * 8];
    short* vd0 = &Vts[sr][((sc2    ) ^ (sr & 7)) * 8];
    short* vd1 = &Vts[sr][((sc2 + 1) ^ (sr & 7)) * 8];

    // swizzled fragment read offsets (row = kt*16 + l16; row&7 == l16&7)
    const int x7 = l16 & 7;

    for (int j0 = 0; j0 < T_DIM; j0 += 64) {
        __syncthreads();                     // prev tile's LDS reads done
        {
            const short* kp = kgbase + (size_t)(j0 + sr) * QKV_LD + sc2 * 8;
            *(short8*)kd0 = *(const short8*)kp;
            *(short8*)kd1 = *(const short8*)(kp + 8);
            const short* vp = vgbase + j0 + sc2 * 8;
            *(short8*)vd0 = *(const short8*)vp;
            *(short8*)vd1 = *(const short8*)(vp + 8);
        }
        __syncthreads();

        // K/V MFMA fragments: read once, reuse for all 4 q-subtiles
        short8 ka[4][2], va[4][2];
        #pragma unroll
        for (int kt = 0; kt < 4; ++kt) {
            const int row = kt * 16 + l16;
            ka[kt][0] = *(const short8*)&Ks[row][((quad    ) ^ x7) * 8];
            ka[kt][1] = *(const short8*)&Ks[row][((quad + 4) ^ x7) * 8];
            va[kt][0] = *(const short8*)&Vts[row][((quad    ) ^ x7) * 8];
            va[kt][1] = *(const short8*)&Vts[row][((quad + 4) ^ x7) * 8];
        }

        #pragma unroll
        for (int sub = 0; sub < QSUB; ++sub) {
            f32x4 s[4];
            #pragma unroll
            for (int kt = 0; kt < 4; ++kt) {
                f32x4 acc = zero4;
                acc = __builtin_amdgcn_mfma_f32_16x16x32_bf16(ka[kt][0], qf[sub][0], acc, 0, 0, 0);
                acc = __builtin_amdgcn_mfma_f32_16x16x32_bf16(ka[kt][1], qf[sub][1], acc, 0, 0, 0);
                s[kt] = acc;
            }

            short8 pa[2];
            #pragma unroll
            for (int hh = 0; hh < 2; ++hh) {
                #pragma unroll
                for (int c = 0; c < 2; ++c) {
                    f32x4 sv = s[2 * hh + c];
                    #pragma unroll
                    for (int r = 0; r < 4; ++r) {
                        float p = __builtin_amdgcn_exp2f(sv[r]);
                        pa[hh][c * 4 + r] = f2bf(p);
                    }
                }
            }

            lacc[sub] = __builtin_amdgcn_mfma_f32_16x16x32_bf16(pa[0], onesv, lacc[sub], 0, 0, 0);
            lacc[sub] = __builtin_amdgcn_mfma_f32_16x16x32_bf16(pa[1], onesv, lacc[sub], 0, 0, 0);

            #pragma unroll
            for (int dg = 0; dg < 4; ++dg) {
                oacc[sub][dg] = __builtin_amdgcn_mfma_f32_16x16x32_bf16(pa[0], va[dg][0], oacc[sub][dg], 0, 0, 0);
                oacc[sub][dg] = __builtin_amdgcn_mfma_f32_16x16x32_bf16(pa[1], va[dg][1], oacc[sub][dg], 0, 0, 0);
            }
        }
    }

    #pragma unroll
    for (int sub = 0; sub < QSUB; ++sub) {
        float linv[4];
        #pragma unroll
        for (int r = 0; r < 4; ++r) linv[r] = 1.0f / lacc[sub][r];

        #pragma unroll
        for (int r = 0; r < 4; ++r) {
            short* orow = O + ((size_t)(b * T_DIM) + i0 + sub * 64 + w * 16 + quad * 4 + r) * C_DIM + h * HS;
            #pragma unroll
            for (int dg = 0; dg < 4; ++dg)
                orow[dg * 16 + l16] = f2bf(oacc[sub][dg][r] * linv[r]);
        }
    }
}

// ---------------------------------------------------------------------------
// ws layout (bytes), NB = 2*M*C = 16.8MB, WB = 2*C*C = 2.1MB:
//   [0]      xb bf16 (reused as Ob after QKV gemm)
//   [NB]     QKVb bf16 [M,3C]  (3*NB)
//   [4NB]    Vt bf16 [B*NH,HS,T]
//   [5NB]    W3b (Wq|Wk|Wv rows, 3*WB) | Wob (WB)      total 92.4MB
// ---------------------------------------------------------------------------
extern "C" void kernel_launch(void* const* d_in, const int* in_sizes, int n_in,
                              void* d_out, int out_size, void* d_ws, size_t ws_size,
                              hipStream_t stream) {
    const float* x  = (const float*)d_in[0];
    const float* Wk = (const float*)d_in[1];
    const float* Wq = (const float*)d_in[2];
    const float* Wv = (const float*)d_in[3];
    const float* Wo = (const float*)d_in[4];
    float* out = (float*)d_out;

    const int M = B_DIM * T_DIM;                       // 8192
    const size_t NE = (size_t)M * C_DIM;               // 8.4M
    const size_t NB = 2 * NE;                          // bytes
    const size_t WB = (size_t)2 * C_DIM * C_DIM;
    const size_t WE = (size_t)C_DIM * C_DIM;           // elements

    char* ws = (char*)d_ws;
    short* xb   = (short*)(ws);
    short* Ob   = xb;                                  // reuse after QKV gemm
    short* QKVb = (short*)(ws + NB);
    short* Vtb  = (short*)(ws + 4 * NB);
    short* W3b  = (short*)(ws + 5 * NB);               // [3C, C] rows: Wq|Wk|Wv (then Wob)
    short* Wob  = (short*)(ws + 5 * NB + 3 * WB);

    // casts: x, then all 4 weights in one launch (Wq pre-scaled by log2(e)/8)
    cast_bf16<<<(int)(NE / 8 / 256), 256, 0, stream>>>(x, xb, (int)(NE / 8), 1.0f);
    const int wn8 = (int)(WE / 8);                     // 131072
    cast4_bf16<<<dim3(wn8 / 256, 4), 256, 0, stream>>>(Wq, Wk, Wv, Wo, W3b, wn8);

    // fused QKV projection: [M,3C] = xb @ W3^T  (8-phase 256^2, grid 384)
    gemm_bt_8ph<<<dim3((QKV_LD / 256) * (M / 256)), 512, 0, stream>>>(
        xb, W3b, QKVb, M, QKV_LD, C_DIM);

    // V transpose to [B*NH, HS, T]
    transpose_v<<<dim3(T_DIM / 64, B_DIM * NHEAD), 256, 0, stream>>>(
        QKVb + 2 * C_DIM, Vtb, QKV_LD);

    // attention (4x q-merge)
    attn_mfma3<<<dim3(T_DIM / (64 * QSUB), B_DIM * NHEAD), 256, 0, stream>>>(
        QKVb, QKVb + C_DIM, Vtb, Ob);

    // output projection (fp32 out)
    gemm_bt_mfma<false><<<dim3(C_DIM / BN, M / BM), 256, 0, stream>>>(
        Ob, Wob, out, M, C_DIM, C_DIM, 1.0f);
}

// Round 6
// 253.513 us; speedup vs baseline: 1.0762x; 1.0359x over previous
//
#include <hip/hip_runtime.h>
#include <hip/hip_bf16.h>
#include <cstddef>
#include <cstdint>

// Problem constants: B=4, T=2048, C=1024, NH=16, hs=64, M = B*T = 8192
#define B_DIM 4
#define T_DIM 2048
#define C_DIM 1024
#define NHEAD 16
#define HS    64
#define QKV_LD 3072   // fused QKV row stride (3*C)

// log2(e)/8 : folded into the Wq bf16 cast so QK^T emerges in exp2-domain.
#define QSCALE 0.18033688011112042f

typedef __attribute__((ext_vector_type(8))) short short8;   // 8 bf16 (MFMA A/B frag)
typedef __attribute__((ext_vector_type(4))) float f32x4;    // MFMA C/D frag

__device__ __forceinline__ short f2bf(float x) {
    __hip_bfloat16 b = __float2bfloat16(x);   // RNE
    return *reinterpret_cast<short*>(&b);
}

// async global->LDS, 16B per lane; LDS dest is wave-uniform base + lane*16.
__device__ __forceinline__ void load_lds16(const void* g, void* l) {
    __builtin_amdgcn_global_load_lds(
        (const __attribute__((address_space(1))) void*)(g),
        (__attribute__((address_space(3))) void*)(l),
        16, 0, 0);
}

// ---------------------------------------------------------------------------
// cast fp32 -> bf16 (with optional fp32 pre-scale), 8 elements/thread
// ---------------------------------------------------------------------------
__global__ __launch_bounds__(256) void cast_bf16(
    const float* __restrict__ in, short* __restrict__ out, int n8, float scale)
{
    int i = blockIdx.x * 256 + threadIdx.x;
    if (i >= n8) return;
    const float4* p = (const float4*)in + (size_t)i * 2;
    float4 a = p[0], b = p[1];
    short8 o;
    o[0]=f2bf(a.x*scale); o[1]=f2bf(a.y*scale); o[2]=f2bf(a.z*scale); o[3]=f2bf(a.w*scale);
    o[4]=f2bf(b.x*scale); o[5]=f2bf(b.y*scale); o[6]=f2bf(b.z*scale); o[7]=f2bf(b.w*scale);
    *((short8*)out + i) = o;
}

// 4 weight matrices (Wq|Wk|Wv|Wo) -> one contiguous bf16 region (W3b|Wob).
// blockIdx.y selects source; Wq gets QSCALE folded in.
__global__ __launch_bounds__(256) void cast4_bf16(
    const float* __restrict__ w0, const float* __restrict__ w1,
    const float* __restrict__ w2, const float* __restrict__ w3,
    short* __restrict__ out, int n8)
{
    int i = blockIdx.x * 256 + threadIdx.x;
    if (i >= n8) return;
    const int sel = blockIdx.y;
    const float* in = (sel == 0) ? w0 : (sel == 1) ? w1 : (sel == 2) ? w2 : w3;
    const float scale = (sel == 0) ? QSCALE : 1.0f;
    const float4* p = (const float4*)in + (size_t)i * 2;
    float4 a = p[0], b = p[1];
    short8 o;
    o[0]=f2bf(a.x*scale); o[1]=f2bf(a.y*scale); o[2]=f2bf(a.z*scale); o[3]=f2bf(a.w*scale);
    o[4]=f2bf(b.x*scale); o[5]=f2bf(b.y*scale); o[6]=f2bf(b.z*scale); o[7]=f2bf(b.w*scale);
    *((short8*)out + (size_t)sel * n8 + i) = o;
}

// ---------------------------------------------------------------------------
// 8-phase-style MFMA GEMM, BM=128 x BN=256 (grid-divisibility variant):
// C[M,N] = A[M,K] @ B[N,K]^T, bf16 in, fp32 accum, bf16 or fp32 out.
// BK=64, 8 waves (2M x 4N), 512 threads, per-wave 64x64 = acc[4][4].
// LDS 96 KiB: Ab0|Ab1 (16KB each) | Bb0|Bb1 (32KB each), double-buffered.
//   -> 1 block/CU, but grids are exact multiples of 256 (full rounds):
//      QKV:  (3072/256)*(8192/128) = 768 = 3 rounds
//      Oproj:(1024/256)*(8192/128) = 256 = 1 round
// Per K-tile t (2 phases of 16 MFMA each):
//   entry:  vmcnt(2) (keeps (t+1).A in flight; 0 on last) + barrier
//   ph0: ds_read B-frags(8)+A-frags mf0,1(4) | stage (t+1).B rows 0-127 |
//        bar | prio1 16xMFMA prio0 | bar
//   ph1: ds_read A-frags mf2,3(4) | stage (t+1).B rows 128-255 |
//        bar | prio1 16xMFMA prio0 | bar
//   tail: stage (t+2).A into just-freed A buffer
// T2: LDS linear for global_load_lds; 16B-chunk XOR'd with (row&7) on the
// GLOBAL source address; same XOR on the ds_read side.
// ---------------------------------------------------------------------------
template<bool OUT_BF16>
__global__ __launch_bounds__(512, 2) void gemm_bt_8ph(
    const short* __restrict__ A,    // [M,K] bf16
    const short* __restrict__ Bm,   // [N,K] bf16
    void* __restrict__ Cm,          // [M,N]
    int M, int N, int K)
{
    __shared__ __align__(16) short lds[49152];   // 96 KiB

    // bijective XCD swizzle (gridDim.x % 8 == 0), then flat -> (bx,by)
    const int nbx = N >> 8;
    int wg = blockIdx.x;
    const int cpx = gridDim.x >> 3;
    wg = (wg & 7) * cpx + (wg >> 3);
    const int bx = wg % nbx, by = wg / nbx;
    const int m0 = by << 7, n0 = bx << 8;        // BM=128, BN=256

    const int t = threadIdx.x;
    const int w = t >> 6, lane = t & 63;
    const int l16 = lane & 15, quad = lane >> 4;
    const int wm = w >> 2, wn = w & 3;           // 2M x 4N waves

    // staging geometry: one call = 64 rows x 128B; thread -> (row, 16B chunk)
    const int rcall  = t >> 3;                   // 0..63
    const int schunk = (t & 7) ^ (rcall & 7);    // pre-swizzled source chunk
    const int dstoff = w * 512;                  // per-wave LDS base (w*8 rows * 64)

    const short* Ag = A  + (size_t)(m0 + rcall) * K + schunk * 8;
    const short* Bg = Bm + (size_t)(n0 + rcall) * K + schunk * 8;

    short* const Ab0 = lds;
    short* const Ab1 = lds + 8192;
    short* const Bb0 = lds + 16384;
    short* const Bb1 = lds + 32768;

    // frag read offsets (shorts), swizzled
    int aoff[4][2], boff[4][2];
    #pragma unroll
    for (int mf = 0; mf < 4; ++mf) {
        const int ar = wm * 64 + mf * 16 + l16;          // 0..127
        #pragma unroll
        for (int ks = 0; ks < 2; ++ks)
            aoff[mf][ks] = ar * 64 + (((ks * 4 + quad) ^ (ar & 7)) * 8);
    }
    #pragma unroll
    for (int nf = 0; nf < 4; ++nf) {
        const int br = wn * 64 + nf * 16 + l16;          // 0..255
        #pragma unroll
        for (int ks = 0; ks < 2; ++ks)
            boff[nf][ks] = br * 64 + (((ks * 4 + quad) ^ (br & 7)) * 8);
    }

    f32x4 acc[4][4];
    const f32x4 zero4 = {0.f, 0.f, 0.f, 0.f};
    #pragma unroll
    for (int mf = 0; mf < 4; ++mf)
        #pragma unroll
        for (int nf = 0; nf < 4; ++nf) acc[mf][nf] = zero4;

    const int NT = K >> 6;   // 64-wide K-tiles

    // one 64-row staging call
    #define ST64(gb, kt, ro, lb)                                               \
        load_lds16((gb) + (size_t)(ro) * K + (size_t)(kt) * 64,                \
                   (lb) + (ro) * 64 + dstoff)

    // prologue: t0.A (2), t0.B (4), t1.A (2)  -> 8 outstanding
    ST64(Ag, 0, 0, Ab0); ST64(Ag, 0, 64, Ab0);
    ST64(Bg, 0, 0, Bb0); ST64(Bg, 0, 64, Bb0);
    ST64(Bg, 0, 128, Bb0); ST64(Bg, 0, 192, Bb0);
    ST64(Ag, 1, 0, Ab1); ST64(Ag, 1, 64, Ab1);

    for (int kt = 0; kt < NT; ++kt) {
        short* Acur = (kt & 1) ? Ab1 : Ab0;
        short* Bcur = (kt & 1) ? Bb1 : Bb0;
        short* Bnx  = (kt & 1) ? Bb0 : Bb1;

        if (kt == NT - 1) asm volatile("s_waitcnt vmcnt(0)" ::: "memory");
        else              asm volatile("s_waitcnt vmcnt(2)" ::: "memory");
        __builtin_amdgcn_s_barrier();

        // ---- phase 0: B-frags (whole tile) + A-frags mf0,1 ----
        short8 bfr[4][2], af[2][2];
        #pragma unroll
        for (int nf = 0; nf < 4; ++nf)
            #pragma unroll
            for (int ks = 0; ks < 2; ++ks)
                bfr[nf][ks] = *(const short8*)(Bcur + boff[nf][ks]);
        #pragma unroll
        for (int mf = 0; mf < 2; ++mf)
            #pragma unroll
            for (int ks = 0; ks < 2; ++ks)
                af[mf][ks] = *(const short8*)(Acur + aoff[mf][ks]);

        if (kt + 1 < NT) { ST64(Bg, kt + 1, 0, Bnx); ST64(Bg, kt + 1, 64, Bnx); }

        __builtin_amdgcn_s_barrier();
        __builtin_amdgcn_s_setprio(1);
        #pragma unroll
        for (int mf = 0; mf < 2; ++mf)
            #pragma unroll
            for (int nf = 0; nf < 4; ++nf)
                #pragma unroll
                for (int ks = 0; ks < 2; ++ks)
                    acc[mf][nf] = __builtin_amdgcn_mfma_f32_16x16x32_bf16(
                        af[mf][ks], bfr[nf][ks], acc[mf][nf], 0, 0, 0);
        __builtin_amdgcn_s_setprio(0);
        __builtin_amdgcn_s_barrier();

        // ---- phase 1: A-frags mf2,3 ----
        short8 af2[2][2];
        #pragma unroll
        for (int mf = 0; mf < 2; ++mf)
            #pragma unroll
            for (int ks = 0; ks < 2; ++ks)
                af2[mf][ks] = *(const short8*)(Acur + aoff[2 + mf][ks]);

        if (kt + 1 < NT) { ST64(Bg, kt + 1, 128, Bnx); ST64(Bg, kt + 1, 192, Bnx); }

        __builtin_amdgcn_s_barrier();
        __builtin_amdgcn_s_setprio(1);
        #pragma unroll
        for (int mf = 0; mf < 2; ++mf)
            #pragma unroll
            for (int nf = 0; nf < 4; ++nf)
                #pragma unroll
                for (int ks = 0; ks < 2; ++ks)
                    acc[2 + mf][nf] = __builtin_amdgcn_mfma_f32_16x16x32_bf16(
                        af2[mf][ks], bfr[nf][ks], acc[2 + mf][nf], 0, 0, 0);
        __builtin_amdgcn_s_setprio(0);
        __builtin_amdgcn_s_barrier();

        // tail: just-freed A buffer -> prefetch (t+2).A
        if (kt + 2 < NT) {
            short* Aw = (kt & 1) ? Ab1 : Ab0;
            ST64(Ag, kt + 2, 0, Aw); ST64(Ag, kt + 2, 64, Aw);
        }
    }
    #undef ST64

    #pragma unroll
    for (int mf = 0; mf < 4; ++mf) {
        const int row_base = m0 + wm * 64 + mf * 16 + quad * 4;
        #pragma unroll
        for (int nf = 0; nf < 4; ++nf) {
            const int col = n0 + wn * 64 + nf * 16 + l16;
            #pragma unroll
            for (int r = 0; r < 4; ++r) {
                const size_t idx = (size_t)(row_base + r) * N + col;
                if (OUT_BF16) ((short*)Cm)[idx] = f2bf(acc[mf][nf][r]);
                else          ((float*)Cm)[idx] = acc[mf][nf][r];
            }
        }
    }
}

// ---------------------------------------------------------------------------
// Transpose V: bf16 [B,T,srcLD] (head-interleaved cols) -> bf16 [B,NH,HS,T]
// ---------------------------------------------------------------------------
__global__ __launch_bounds__(256) void transpose_v(
    const short* __restrict__ Vb,
    short* __restrict__ Vt, int srcLD)
{
    const int t0 = blockIdx.x * 64;
    const int head = blockIdx.y;              // b*NHEAD + h
    const int b = head >> 4, h = head & 15;

    __shared__ short Ls[64][72];

    const int t = threadIdx.x;
    const int r = t >> 2;
    const int c = (t & 3) * 16;

    const short* src = Vb + ((size_t)(b * T_DIM) + t0 + r) * srcLD + h * HS + c;
    *(short8*)&Ls[r][c]     = *(const short8*)src;
    *(short8*)&Ls[r][c + 8] = *(const short8*)(src + 8);
    __syncthreads();

    short tmp[16];
    #pragma unroll
    for (int i = 0; i < 16; ++i) tmp[i] = Ls[c + i][r];
    short* dst = Vt + ((size_t)head * HS + r) * T_DIM + t0 + c;
    *(short8*)dst       = *(short8*)&tmp[0];
    *(short8*)(dst + 8) = *(short8*)&tmp[8];
}

// ---------------------------------------------------------------------------
// Flash attention v6: R2 structure + T2 chunk-XOR LDS swizzle.
//  - Ks/Vts are [64][64] (128B rows); 16B chunk c of physical row r is
//    stored at chunk (c ^ (r&7)). Same XOR applied on the reg-staged write
//    and the fragment ds_read_b128 -> bank-conflict-free (T2, m214 v20).
//  - Q pre-scaled by log2(e)/8 at the Wq cast -> exp is a bare v_exp_f32.
//  - Row-sum l computed by MFMA against a ones B-fragment.
// One block = one (b,h) head x 256 q-rows (4 subtiles of 64); 4 waves.
// S^T trick: A=K-frag, B=Q-frag -> D[key][q]; K rows permuted kappa^-1 so
// exp'd S^T regs concatenate directly into the PV A-fragment. No-max softmax.
// ---------------------------------------------------------------------------
#define QSUB 4

__global__ __launch_bounds__(256, 2) void attn_mfma3(
    const short* __restrict__ Qb,    // [B,T,QKV_LD], Q cols (pre-scaled)
    const short* __restrict__ Kb,    // [B,T,QKV_LD], K cols
    const short* __restrict__ Vt,    // [B*NH, HS, T]
    short* __restrict__ O)           // [B,T,C] bf16
{
    const int i0   = blockIdx.x * (64 * QSUB);
    const int head = blockIdx.y;
    const int b = head >> 4, h = head & 15;

    const int t    = threadIdx.x;
    const int w    = t >> 6;
    const int lane = t & 63;
    const int l16  = lane & 15;
    const int quad = lane >> 4;

    __shared__ __align__(16) short Ks[64][64];    // [perm key][dim], chunk-swizzled
    __shared__ __align__(16) short Vts[64][64];   // [dim][key],     chunk-swizzled

    short8 qf[QSUB][2];
    #pragma unroll
    for (int sub = 0; sub < QSUB; ++sub) {
        const short* qrow = Qb
            + ((size_t)(b * T_DIM) + i0 + sub * 64 + w * 16 + l16) * QKV_LD + h * HS;
        qf[sub][0] = *(const short8*)(qrow + quad * 8);
        qf[sub][1] = *(const short8*)(qrow + 32 + quad * 8);
    }

    short8 onesv;
    #pragma unroll
    for (int j = 0; j < 8; ++j) onesv[j] = (short)0x3F80;

    const f32x4 zero4 = {0.f, 0.f, 0.f, 0.f};
    f32x4 oacc[QSUB][4];
    f32x4 lacc[QSUB];
    #pragma unroll
    for (int sub = 0; sub < QSUB; ++sub) {
        #pragma unroll
        for (int dg = 0; dg < 4; ++dg) oacc[sub][dg] = zero4;
        lacc[sub] = zero4;
    }

    const int sr  = t >> 2;                  // staging row 0..63
    const int sc2 = (t & 3) * 2;             // first of two 16B chunks
    const int krow = (sr & 32) | ((sr & 4) << 2) | ((sr & 24) >> 1) | (sr & 3);
    const short* kgbase = Kb + (size_t)(b * T_DIM) * QKV_LD + h * HS;
    const short* vgbase = Vt + ((size_t)head * HS + sr) * T_DIM;

    // swizzled staging destinations (fixed per thread)
    short* kd0 = &Ks[krow][((sc2    ) ^ (krow & 7)) * 8];
    short* kd1 = &Ks[krow][((sc2 + 1) ^ (krow & 7)) * 8];
    short* vd0 = &Vts[sr][((sc2    ) ^ (sr & 7)) * 8];
    short* vd1 = &Vts[sr][((sc2 + 1) ^ (sr & 7)) * 8];

    // swizzled fragment read offsets (row = kt*16 + l16; row&7 == l16&7)
    const int x7 = l16 & 7;

    for (int j0 = 0; j0 < T_DIM; j0 += 64) {
        __syncthreads();                     // prev tile's LDS reads done
        {
            const short* kp = kgbase + (size_t)(j0 + sr) * QKV_LD + sc2 * 8;
            *(short8*)kd0 = *(const short8*)kp;
            *(short8*)kd1 = *(const short8*)(kp + 8);
            const short* vp = vgbase + j0 + sc2 * 8;
            *(short8*)vd0 = *(const short8*)vp;
            *(short8*)vd1 = *(const short8*)(vp + 8);
        }
        __syncthreads();

        // K/V MFMA fragments: read once, reuse for all 4 q-subtiles
        short8 ka[4][2], va[4][2];
        #pragma unroll
        for (int kt = 0; kt < 4; ++kt) {
            const int row = kt * 16 + l16;
            ka[kt][0] = *(const short8*)&Ks[row][((quad    ) ^ x7) * 8];
            ka[kt][1] = *(const short8*)&Ks[row][((quad + 4) ^ x7) * 8];
            va[kt][0] = *(const short8*)&Vts[row][((quad    ) ^ x7) * 8];
            va[kt][1] = *(const short8*)&Vts[row][((quad + 4) ^ x7) * 8];
        }

        #pragma unroll
        for (int sub = 0; sub < QSUB; ++sub) {
            f32x4 s[4];
            #pragma unroll
            for (int kt = 0; kt < 4; ++kt) {
                f32x4 acc = zero4;
                acc = __builtin_amdgcn_mfma_f32_16x16x32_bf16(ka[kt][0], qf[sub][0], acc, 0, 0, 0);
                acc = __builtin_amdgcn_mfma_f32_16x16x32_bf16(ka[kt][1], qf[sub][1], acc, 0, 0, 0);
                s[kt] = acc;
            }

            short8 pa[2];
            #pragma unroll
            for (int hh = 0; hh < 2; ++hh) {
                #pragma unroll
                for (int c = 0; c < 2; ++c) {
                    f32x4 sv = s[2 * hh + c];
                    #pragma unroll
                    for (int r = 0; r < 4; ++r) {
                        float p = __builtin_amdgcn_exp2f(sv[r]);
                        pa[hh][c * 4 + r] = f2bf(p);
                    }
                }
            }

            lacc[sub] = __builtin_amdgcn_mfma_f32_16x16x32_bf16(pa[0], onesv, lacc[sub], 0, 0, 0);
            lacc[sub] = __builtin_amdgcn_mfma_f32_16x16x32_bf16(pa[1], onesv, lacc[sub], 0, 0, 0);

            #pragma unroll
            for (int dg = 0; dg < 4; ++dg) {
                oacc[sub][dg] = __builtin_amdgcn_mfma_f32_16x16x32_bf16(pa[0], va[dg][0], oacc[sub][dg], 0, 0, 0);
                oacc[sub][dg] = __builtin_amdgcn_mfma_f32_16x16x32_bf16(pa[1], va[dg][1], oacc[sub][dg], 0, 0, 0);
            }
        }
    }

    #pragma unroll
    for (int sub = 0; sub < QSUB; ++sub) {
        float linv[4];
        #pragma unroll
        for (int r = 0; r < 4; ++r) linv[r] = 1.0f / lacc[sub][r];

        #pragma unroll
        for (int r = 0; r < 4; ++r) {
            short* orow = O + ((size_t)(b * T_DIM) + i0 + sub * 64 + w * 16 + quad * 4 + r) * C_DIM + h * HS;
            #pragma unroll
            for (int dg = 0; dg < 4; ++dg)
                orow[dg * 16 + l16] = f2bf(oacc[sub][dg][r] * linv[r]);
        }
    }
}

// ---------------------------------------------------------------------------
// ws layout (bytes), NB = 2*M*C = 16.8MB, WB = 2*C*C = 2.1MB:
//   [0]      xb bf16 (reused as Ob after QKV gemm)
//   [NB]     QKVb bf16 [M,3C]  (3*NB)
//   [4NB]    Vt bf16 [B*NH,HS,T]
//   [5NB]    W3b (Wq|Wk|Wv rows, 3*WB) | Wob (WB)      total 92.4MB
// ---------------------------------------------------------------------------
extern "C" void kernel_launch(void* const* d_in, const int* in_sizes, int n_in,
                              void* d_out, int out_size, void* d_ws, size_t ws_size,
                              hipStream_t stream) {
    const float* x  = (const float*)d_in[0];
    const float* Wk = (const float*)d_in[1];
    const float* Wq = (const float*)d_in[2];
    const float* Wv = (const float*)d_in[3];
    const float* Wo = (const float*)d_in[4];
    float* out = (float*)d_out;

    const int M = B_DIM * T_DIM;                       // 8192
    const size_t NE = (size_t)M * C_DIM;               // 8.4M
    const size_t NB = 2 * NE;                          // bytes
    const size_t WB = (size_t)2 * C_DIM * C_DIM;
    const size_t WE = (size_t)C_DIM * C_DIM;           // elements

    char* ws = (char*)d_ws;
    short* xb   = (short*)(ws);
    short* Ob   = xb;                                  // reuse after QKV gemm
    short* QKVb = (short*)(ws + NB);
    short* Vtb  = (short*)(ws + 4 * NB);
    short* W3b  = (short*)(ws + 5 * NB);               // [3C, C] rows: Wq|Wk|Wv (then Wob)
    short* Wob  = (short*)(ws + 5 * NB + 3 * WB);

    // casts: x, then all 4 weights in one launch (Wq pre-scaled by log2(e)/8)
    cast_bf16<<<(int)(NE / 8 / 256), 256, 0, stream>>>(x, xb, (int)(NE / 8), 1.0f);
    const int wn8 = (int)(WE / 8);                     // 131072
    cast4_bf16<<<dim3(wn8 / 256, 4), 256, 0, stream>>>(Wq, Wk, Wv, Wo, W3b, wn8);

    // fused QKV projection: [M,3C] = xb @ W3^T  (BM128xBN256, grid 768 = 3 rounds)
    gemm_bt_8ph<true><<<dim3((QKV_LD / 256) * (M / 128)), 512, 0, stream>>>(
        xb, W3b, QKVb, M, QKV_LD, C_DIM);

    // V transpose to [B*NH, HS, T]
    transpose_v<<<dim3(T_DIM / 64, B_DIM * NHEAD), 256, 0, stream>>>(
        QKVb + 2 * C_DIM, Vtb, QKV_LD);

    // attention (4x q-merge)
    attn_mfma3<<<dim3(T_DIM / (64 * QSUB), B_DIM * NHEAD), 256, 0, stream>>>(
        QKVb, QKVb + C_DIM, Vtb, Ob);

    // output projection (fp32 out; grid 256 = exactly 1 full round)
    gemm_bt_8ph<false><<<dim3((C_DIM / 256) * (M / 128)), 512, 0, stream>>>(
        Ob, Wob, out, M, C_DIM, C_DIM);
}